// Round 1
// baseline (1581.210 us; speedup 1.0000x reference)
//
#include <hip/hip_runtime.h>
#include <math.h>

#define NN 100000
#define NE 1600000
// DIN=128, DH=128, DOUT=64, NL=10

// ---------------- setup kernels ----------------

__global__ __launch_bounds__(256) void count_k(const int* __restrict__ dst, int* __restrict__ cnt) {
  int e = blockIdx.x * 256 + threadIdx.x;
  if (e < NE) atomicAdd(&cnt[dst[e]], 1);
}

__global__ __launch_bounds__(256) void dinv_k(const int* __restrict__ cnt, float* __restrict__ dinv) {
  int i = blockIdx.x * 256 + threadIdx.x;
  if (i < NN) dinv[i] = rsqrtf((float)(cnt[i] + 1));  // +1 self-loop; always > 0
}

__global__ __launch_bounds__(1024) void scan1(const int* __restrict__ cnt, int* __restrict__ rowstart,
                                              int* __restrict__ blocksum) {
  __shared__ int s[1024];
  int t = threadIdx.x;
  int i = blockIdx.x * 1024 + t;
  int v = (i < NN) ? cnt[i] : 0;
  s[t] = v;
  __syncthreads();
  for (int off = 1; off < 1024; off <<= 1) {
    int add = (t >= off) ? s[t - off] : 0;
    __syncthreads();
    s[t] += add;
    __syncthreads();
  }
  if (i < NN) rowstart[i] = s[t] - v;   // exclusive
  if (t == 1023) blocksum[blockIdx.x] = s[1023];
}

__global__ void scan2(int* blocksum, int nb) {
  if (threadIdx.x == 0 && blockIdx.x == 0) {
    int acc = 0;
    for (int b = 0; b < nb; ++b) { int v = blocksum[b]; blocksum[b] = acc; acc += v; }
  }
}

__global__ __launch_bounds__(1024) void scan3(int* __restrict__ rowstart, const int* __restrict__ blocksum) {
  int i = blockIdx.x * 1024 + threadIdx.x;
  if (i < NN) rowstart[i] += blocksum[blockIdx.x];
}

__global__ __launch_bounds__(256) void fill_k(const int* __restrict__ src, const int* __restrict__ dst,
                                              const int* __restrict__ rowstart, int* __restrict__ cursor,
                                              int* __restrict__ csr) {
  int e = blockIdx.x * 256 + threadIdx.x;
  if (e < NE) {
    int d = dst[e];
    int pos = rowstart[d] + atomicAdd(&cursor[d], 1);
    csr[pos] = src[e];
  }
}

// ---------------- dense GEMM: C[i,c] = act(scale_i * sum_k A[i,k] W[k,c] (+bias)) ----------------
// A = [A1 | A2] concatenated on K. Thread tile 4 rows x 4 cols. (DC/4)*(ROWS/4)==256.
// ACT: 0=none, 1=relu, 2=sigmoid. PRESCALE: multiply row by dinv[i].

template <int K1, int K2, int DC, int ROWS, int ACT, bool PRESCALE, bool BIAS>
__global__ __launch_bounds__(256) void gemm_k(const float* __restrict__ A1, const float* __restrict__ A2,
                                              const float* __restrict__ W, const float* __restrict__ bias,
                                              const float* __restrict__ dinv, float* __restrict__ C) {
  constexpr int K = K1 + K2;
  static_assert((DC / 4) * (ROWS / 4) == 256, "thread map");
  __shared__ float Ws[K * DC];
  __shared__ float Xs[K * ROWS];  // transposed: Xs[k*ROWS + r], XOR-swizzled on r
  const int tid = threadIdx.x;
  const int row0 = blockIdx.x * ROWS;

  // stage W (coalesced float4)
  for (int idx = tid * 4; idx < K * DC; idx += 1024)
    *(float4*)&Ws[idx] = *(const float4*)&W[idx];

  // stage A transposed: thread loads 4 rows at one k (coalesced over k across lanes)
  for (int idx = tid; idx < K * (ROWS / 4); idx += 256) {
    int k = idx % K;
    int r0 = (idx / K) * 4;
    int g0 = row0 + r0;
    int gr0 = min(g0 + 0, NN - 1);
    int gr1 = min(g0 + 1, NN - 1);
    int gr2 = min(g0 + 2, NN - 1);
    int gr3 = min(g0 + 3, NN - 1);
    float4 v;
    if constexpr (K2 > 0) {
      if (k < K1) {
        v.x = A1[(size_t)gr0 * K1 + k]; v.y = A1[(size_t)gr1 * K1 + k];
        v.z = A1[(size_t)gr2 * K1 + k]; v.w = A1[(size_t)gr3 * K1 + k];
      } else {
        int kk = k - K1;
        v.x = A2[(size_t)gr0 * K2 + kk]; v.y = A2[(size_t)gr1 * K2 + kk];
        v.z = A2[(size_t)gr2 * K2 + kk]; v.w = A2[(size_t)gr3 * K2 + kk];
      }
    } else {
      v.x = A1[(size_t)gr0 * K1 + k]; v.y = A1[(size_t)gr1 * K1 + k];
      v.z = A1[(size_t)gr2 * K1 + k]; v.w = A1[(size_t)gr3 * K1 + k];
    }
    *(float4*)&Xs[k * ROWS + (r0 ^ ((k & 7) << 2))] = v;
  }
  __syncthreads();

  const int cg = tid % (DC / 4);
  const int rg = tid / (DC / 4);
  const int c0 = cg * 4, r0 = rg * 4;
  float acc[4][4] = {};
#pragma unroll 8
  for (int k = 0; k < K; ++k) {
    float4 wv = *(const float4*)&Ws[k * DC + c0];
    float4 xv = *(const float4*)&Xs[k * ROWS + (r0 ^ ((k & 7) << 2))];
    float xr[4] = {xv.x, xv.y, xv.z, xv.w};
    float wr[4] = {wv.x, wv.y, wv.z, wv.w};
#pragma unroll
    for (int i = 0; i < 4; ++i)
#pragma unroll
      for (int j = 0; j < 4; ++j) acc[i][j] = fmaf(xr[i], wr[j], acc[i][j]);
  }

#pragma unroll
  for (int i = 0; i < 4; ++i) {
    int grow = row0 + r0 + i;
    if (grow < NN) {
      float s = 1.0f;
      if (PRESCALE) s = dinv[grow];
      float o[4];
#pragma unroll
      for (int j = 0; j < 4; ++j) o[j] = acc[i][j] * s;
      if (BIAS) {
        float4 bv = *(const float4*)&bias[c0];
        o[0] += bv.x; o[1] += bv.y; o[2] += bv.z; o[3] += bv.w;
      }
      if (ACT == 1) {
#pragma unroll
        for (int j = 0; j < 4; ++j) o[j] = fmaxf(o[j], 0.0f);
      } else if (ACT == 2) {
#pragma unroll
        for (int j = 0; j < 4; ++j) o[j] = 1.0f / (1.0f + __expf(-o[j]));
      }
      float4 ov = {o[0], o[1], o[2], o[3]};
      *(float4*)&C[(size_t)grow * DC + c0] = ov;
    }
  }
}

// ---------------- aggregation: out[i] = act(dinv[i]*(t[i] + sum_{e->i} t[src_e]) + b) ----------------
// D/4 lanes per node, float4 gathers.

template <int D, int ACT>
__global__ __launch_bounds__(256) void agg_k(const float* __restrict__ t, const int* __restrict__ rowstart,
                                             const int* __restrict__ cnt, const int* __restrict__ csr,
                                             const float* __restrict__ dinv, const float* __restrict__ bias,
                                             float* __restrict__ out) {
  constexpr int LPN = D / 4;
  int node = blockIdx.x * (256 / LPN) + threadIdx.x / LPN;
  int lane = threadIdx.x % LPN;
  if (node >= NN) return;
  size_t base = (size_t)node * D + lane * 4;
  float4 acc = *(const float4*)&t[base];  // self-loop
  int s = rowstart[node];
  int c = cnt[node];
  for (int j = 0; j < c; ++j) {
    int sn = csr[s + j];
    float4 v = *(const float4*)&t[(size_t)sn * D + lane * 4];
    acc.x += v.x; acc.y += v.y; acc.z += v.z; acc.w += v.w;
  }
  float dv = dinv[node];
  float4 bv = *(const float4*)&bias[lane * 4];
  float o[4] = {acc.x * dv + bv.x, acc.y * dv + bv.y, acc.z * dv + bv.z, acc.w * dv + bv.w};
  if (ACT == 1) {
#pragma unroll
    for (int j = 0; j < 4; ++j) o[j] = fmaxf(o[j], 0.0f);
  }
  float4 ov = {o[0], o[1], o[2], o[3]};
  *(float4*)&out[base] = ov;
}

// ---------------- launch ----------------

extern "C" void kernel_launch(void* const* d_in, const int* in_sizes, int n_in,
                              void* d_out, int out_size, void* d_ws, size_t ws_size,
                              hipStream_t stream) {
  const float* x  = (const float*)d_in[0];
  const float* y  = (const float*)d_in[1];
  const int* ei   = (const int*)d_in[2];
  const float* Wg1 = (const float*)d_in[3];
  const float* bg1 = (const float*)d_in[4];
  const float* Wg2 = (const float*)d_in[5];
  const float* bg2 = (const float*)d_in[6];
  const float* Wl  = (const float*)d_in[7];
  const float* bl  = (const float*)d_in[8];
  const float* Wf  = (const float*)d_in[9];
  const float* bf  = (const float*)d_in[10];
  float* out = (float*)d_out;

  char* ws = (char*)d_ws;
  size_t off = 0;
  auto alloc = [&](size_t bytes) { void* p = ws + off; off += (bytes + 511) & ~(size_t)511; return p; };
  int* cnt      = (int*)alloc((size_t)NN * 4);
  int* cursor   = (int*)alloc((size_t)NN * 4);
  int* rowstart = (int*)alloc((size_t)NN * 4);
  int* blocksum = (int*)alloc(512);
  float* dinv   = (float*)alloc((size_t)NN * 4);
  int* csr      = (int*)alloc((size_t)NE * 4);
  float* T      = (float*)alloc((size_t)NN * 128 * 4);
  float* H      = (float*)alloc((size_t)NN * 128 * 4);
  float* U      = (float*)alloc((size_t)NN * 64 * 4);
  float* XL0 = T;                           // label ping-pong reuses T (free after feature branch)
  float* XL1 = T + (size_t)NN * 64;

  const int* esrc = ei;
  const int* edst = ei + NE;

  hipMemsetAsync(cnt, 0, (size_t)NN * 4, stream);
  hipMemsetAsync(cursor, 0, (size_t)NN * 4, stream);
  count_k<<<NE / 256, 256, 0, stream>>>(edst, cnt);
  dinv_k<<<(NN + 255) / 256, 256, 0, stream>>>(cnt, dinv);
  scan1<<<98, 1024, 0, stream>>>(cnt, rowstart, blocksum);
  scan2<<<1, 1, 0, stream>>>(blocksum, 98);
  scan3<<<98, 1024, 0, stream>>>(rowstart, blocksum);
  fill_k<<<NE / 256, 256, 0, stream>>>(esrc, edst, rowstart, cursor, csr);

  // feature branch: h = relu(gcn(x,Wg1,bg1)); h2 = gcn(h,Wg2,bg2)
  gemm_k<128, 0, 128, 32, 0, true, false><<<NN / 32, 256, 0, stream>>>(x, nullptr, Wg1, nullptr, dinv, T);
  agg_k<128, 1><<<NN / 8, 256, 0, stream>>>(T, rowstart, cnt, csr, dinv, bg1, H);
  gemm_k<128, 0, 128, 32, 0, true, false><<<NN / 32, 256, 0, stream>>>(H, nullptr, Wg2, nullptr, dinv, T);
  agg_k<128, 0><<<NN / 8, 256, 0, stream>>>(T, rowstart, cnt, csr, dinv, bg2, H);

  // label branch: 10 layers, relu except last
  const float* xl = y;
  for (int j = 0; j < 10; ++j) {
    gemm_k<64, 0, 64, 64, 0, true, false><<<(NN + 63) / 64, 256, 0, stream>>>(
        xl, nullptr, Wl + (size_t)j * 64 * 64, nullptr, dinv, U);
    float* nxt = (j & 1) ? XL1 : XL0;
    if (j < 9)
      agg_k<64, 1><<<NN / 16, 256, 0, stream>>>(U, rowstart, cnt, csr, dinv, bl + (size_t)j * 64, nxt);
    else
      agg_k<64, 0><<<NN / 16, 256, 0, stream>>>(U, rowstart, cnt, csr, dinv, bl + (size_t)j * 64, nxt);
    xl = nxt;
  }

  // fused head: sigmoid([h2 | xl] @ Wf + bf), xl ended in XL1 (j=9 odd)
  gemm_k<128, 64, 64, 64, 2, false, true><<<(NN + 63) / 64, 256, 0, stream>>>(H, xl, Wf, bf, nullptr, out);
}

// Round 2
// 1187.514 us; speedup vs baseline: 1.3315x; 1.3315x over previous
//
#include <hip/hip_runtime.h>
#include <math.h>

#define NN 100000
#define NE 1600000
// DIN=128, DH=128, DOUT=64, NL=10

typedef unsigned short ushort_t;
typedef unsigned int uint_t;

__device__ __forceinline__ ushort_t f2bf(float f) {
  uint_t u = __float_as_uint(f);
  u = (u + 0x7fffu + ((u >> 16) & 1u)) >> 16;   // round-to-nearest-even
  return (ushort_t)u;
}

// ---------------- setup kernels ----------------

__global__ __launch_bounds__(256) void count_k(const int* __restrict__ dst, int* __restrict__ cnt) {
  int e = blockIdx.x * 256 + threadIdx.x;
  if (e < NE) atomicAdd(&cnt[dst[e]], 1);
}

__global__ __launch_bounds__(256) void dinv_k(const int* __restrict__ cnt, float* __restrict__ dinv) {
  int i = blockIdx.x * 256 + threadIdx.x;
  if (i < NN) dinv[i] = rsqrtf((float)(cnt[i] + 1));  // +1 self-loop; always > 0
}

__global__ __launch_bounds__(1024) void scan1(const int* __restrict__ cnt, int* __restrict__ rowstart,
                                              int* __restrict__ blocksum) {
  __shared__ int s[1024];
  int t = threadIdx.x;
  int i = blockIdx.x * 1024 + t;
  int v = (i < NN) ? cnt[i] : 0;
  s[t] = v;
  __syncthreads();
  for (int off = 1; off < 1024; off <<= 1) {
    int add = (t >= off) ? s[t - off] : 0;
    __syncthreads();
    s[t] += add;
    __syncthreads();
  }
  if (i < NN) rowstart[i] = s[t] - v;   // exclusive
  if (t == 1023) blocksum[blockIdx.x] = s[1023];
}

__global__ void scan2(int* blocksum, int nb) {
  if (threadIdx.x == 0 && blockIdx.x == 0) {
    int acc = 0;
    for (int b = 0; b < nb; ++b) { int v = blocksum[b]; blocksum[b] = acc; acc += v; }
  }
}

__global__ __launch_bounds__(1024) void scan3(int* __restrict__ rowstart, const int* __restrict__ blocksum) {
  int i = blockIdx.x * 1024 + threadIdx.x;
  if (i < NN) rowstart[i] += blocksum[blockIdx.x];
}

__global__ __launch_bounds__(256) void fill_k(const int* __restrict__ src, const int* __restrict__ dst,
                                              const int* __restrict__ rowstart, int* __restrict__ cursor,
                                              int* __restrict__ csr) {
  int e = blockIdx.x * 256 + threadIdx.x;
  if (e < NE) {
    int d = dst[e];
    int pos = rowstart[d] + atomicAdd(&cursor[d], 1);
    csr[pos] = src[e];
  }
}

// ---------------- dense GEMM: C[i,c] = act(scale_i * sum_k A[i,k] W[k,c] (+bias)) ----------------
// A = [A1 | A2] concatenated on K. Thread tile 4 rows x 4 cols. (DC/4)*(ROWS/4)==256.
// ACT: 0=none, 1=relu, 2=sigmoid. PRESCALE: multiply row by dinv[i]. BF16OUT: store bf16.

template <int K1, int K2, int DC, int ROWS, int ACT, bool PRESCALE, bool BIAS, bool BF16OUT>
__global__ __launch_bounds__(256) void gemm_k(const float* __restrict__ A1, const float* __restrict__ A2,
                                              const float* __restrict__ W, const float* __restrict__ bias,
                                              const float* __restrict__ dinv, void* __restrict__ Cv) {
  constexpr int K = K1 + K2;
  static_assert((DC / 4) * (ROWS / 4) == 256, "thread map");
  __shared__ float Ws[K * DC];
  __shared__ float Xs[K * ROWS];  // transposed: Xs[k*ROWS + r], XOR-swizzled on r
  const int tid = threadIdx.x;
  const int row0 = blockIdx.x * ROWS;

  // stage W (coalesced float4)
  for (int idx = tid * 4; idx < K * DC; idx += 1024)
    *(float4*)&Ws[idx] = *(const float4*)&W[idx];

  // stage A transposed: thread loads 4 rows at one k (coalesced over k across lanes)
  for (int idx = tid; idx < K * (ROWS / 4); idx += 256) {
    int k = idx % K;
    int r0 = (idx / K) * 4;
    int g0 = row0 + r0;
    int gr0 = min(g0 + 0, NN - 1);
    int gr1 = min(g0 + 1, NN - 1);
    int gr2 = min(g0 + 2, NN - 1);
    int gr3 = min(g0 + 3, NN - 1);
    float4 v;
    if constexpr (K2 > 0) {
      if (k < K1) {
        v.x = A1[(size_t)gr0 * K1 + k]; v.y = A1[(size_t)gr1 * K1 + k];
        v.z = A1[(size_t)gr2 * K1 + k]; v.w = A1[(size_t)gr3 * K1 + k];
      } else {
        int kk = k - K1;
        v.x = A2[(size_t)gr0 * K2 + kk]; v.y = A2[(size_t)gr1 * K2 + kk];
        v.z = A2[(size_t)gr2 * K2 + kk]; v.w = A2[(size_t)gr3 * K2 + kk];
      }
    } else {
      v.x = A1[(size_t)gr0 * K1 + k]; v.y = A1[(size_t)gr1 * K1 + k];
      v.z = A1[(size_t)gr2 * K1 + k]; v.w = A1[(size_t)gr3 * K1 + k];
    }
    *(float4*)&Xs[k * ROWS + (r0 ^ ((k & 7) << 2))] = v;
  }
  __syncthreads();

  const int cg = tid % (DC / 4);
  const int rg = tid / (DC / 4);
  const int c0 = cg * 4, r0 = rg * 4;
  float acc[4][4] = {};
#pragma unroll 8
  for (int k = 0; k < K; ++k) {
    float4 wv = *(const float4*)&Ws[k * DC + c0];
    float4 xv = *(const float4*)&Xs[k * ROWS + (r0 ^ ((k & 7) << 2))];
    float xr[4] = {xv.x, xv.y, xv.z, xv.w};
    float wr[4] = {wv.x, wv.y, wv.z, wv.w};
#pragma unroll
    for (int i = 0; i < 4; ++i)
#pragma unroll
      for (int j = 0; j < 4; ++j) acc[i][j] = fmaf(xr[i], wr[j], acc[i][j]);
  }

#pragma unroll
  for (int i = 0; i < 4; ++i) {
    int grow = row0 + r0 + i;
    if (grow < NN) {
      float s = 1.0f;
      if (PRESCALE) s = dinv[grow];
      float o[4];
#pragma unroll
      for (int j = 0; j < 4; ++j) o[j] = acc[i][j] * s;
      if (BIAS) {
        float4 bv = *(const float4*)&bias[c0];
        o[0] += bv.x; o[1] += bv.y; o[2] += bv.z; o[3] += bv.w;
      }
      if (ACT == 1) {
#pragma unroll
        for (int j = 0; j < 4; ++j) o[j] = fmaxf(o[j], 0.0f);
      } else if (ACT == 2) {
#pragma unroll
        for (int j = 0; j < 4; ++j) o[j] = 1.0f / (1.0f + __expf(-o[j]));
      }
      if constexpr (BF16OUT) {
        ushort4 pv;
        pv.x = f2bf(o[0]); pv.y = f2bf(o[1]); pv.z = f2bf(o[2]); pv.w = f2bf(o[3]);
        *(ushort4*)&((ushort_t*)Cv)[(size_t)grow * DC + c0] = pv;
      } else {
        float4 ov = {o[0], o[1], o[2], o[3]};
        *(float4*)&((float*)Cv)[(size_t)grow * DC + c0] = ov;
      }
    }
  }
}

// ---------------- aggregation (bf16 input rows, f32 accum/output) ----------------
// out[i] = act(dinv[i]*(t[i] + sum_{e->i} t[src_e]) + b).  D/8 lanes per node, 16B gathers.

template <int D, int ACT>
__global__ __launch_bounds__(256) void agg_k(const uint4* __restrict__ t, const int* __restrict__ rowstart,
                                             const int* __restrict__ cnt, const int* __restrict__ csr,
                                             const float* __restrict__ dinv, const float* __restrict__ bias,
                                             float* __restrict__ out) {
  constexpr int LPN = D / 8;  // lanes per node, 8 bf16 (16B) per lane
  int node = blockIdx.x * (256 / LPN) + threadIdx.x / LPN;
  int lane = threadIdx.x % LPN;
  if (node >= NN) return;

  float acc[8];
  uint4 sv = t[(size_t)node * LPN + lane];  // self row
  {
    uint_t u[4] = {sv.x, sv.y, sv.z, sv.w};
#pragma unroll
    for (int q = 0; q < 4; ++q) {
      acc[2 * q]     = __uint_as_float(u[q] << 16);
      acc[2 * q + 1] = __uint_as_float(u[q] & 0xffff0000u);
    }
  }
  int s = rowstart[node];
  int c = cnt[node];
  for (int j = 0; j < c; ++j) {
    int sn = csr[s + j];
    uint4 v = t[(size_t)sn * LPN + lane];
    uint_t u[4] = {v.x, v.y, v.z, v.w};
#pragma unroll
    for (int q = 0; q < 4; ++q) {
      acc[2 * q]     += __uint_as_float(u[q] << 16);
      acc[2 * q + 1] += __uint_as_float(u[q] & 0xffff0000u);
    }
  }
  float dv = dinv[node];
  float o[8];
#pragma unroll
  for (int q = 0; q < 8; ++q) {
    o[q] = acc[q] * dv + bias[lane * 8 + q];
    if (ACT == 1) o[q] = fmaxf(o[q], 0.0f);
  }
  size_t base = (size_t)node * D + lane * 8;
  float4 o0 = {o[0], o[1], o[2], o[3]};
  float4 o1 = {o[4], o[5], o[6], o[7]};
  *(float4*)&out[base] = o0;
  *(float4*)&out[base + 4] = o1;
}

// ---------------- launch ----------------

extern "C" void kernel_launch(void* const* d_in, const int* in_sizes, int n_in,
                              void* d_out, int out_size, void* d_ws, size_t ws_size,
                              hipStream_t stream) {
  const float* x  = (const float*)d_in[0];
  const float* y  = (const float*)d_in[1];
  const int* ei   = (const int*)d_in[2];
  const float* Wg1 = (const float*)d_in[3];
  const float* bg1 = (const float*)d_in[4];
  const float* Wg2 = (const float*)d_in[5];
  const float* bg2 = (const float*)d_in[6];
  const float* Wl  = (const float*)d_in[7];
  const float* bl  = (const float*)d_in[8];
  const float* Wf  = (const float*)d_in[9];
  const float* bf  = (const float*)d_in[10];
  float* out = (float*)d_out;

  char* ws = (char*)d_ws;
  size_t off = 0;
  auto alloc = [&](size_t bytes) { void* p = ws + off; off += (bytes + 511) & ~(size_t)511; return p; };
  int* cnt      = (int*)alloc((size_t)NN * 4);
  int* cursor   = (int*)alloc((size_t)NN * 4);
  int* rowstart = (int*)alloc((size_t)NN * 4);
  int* blocksum = (int*)alloc(512);
  float* dinv   = (float*)alloc((size_t)NN * 4);
  int* csr      = (int*)alloc((size_t)NE * 4);
  ushort_t* Tb  = (ushort_t*)alloc((size_t)NN * 128 * 2);  // bf16 GEMM->agg buffer (feature branch)
  float* H      = (float*)alloc((size_t)NN * 128 * 4);     // f32 agg output / GEMM input
  ushort_t* Ub  = (ushort_t*)alloc((size_t)NN * 64 * 2);   // bf16 GEMM->agg buffer (label branch)
  float* XL1    = (float*)alloc((size_t)NN * 64 * 4);      // label ping
  float* XL0    = (float*)Tb;                              // label pong aliases Tb (free after feature branch)

  const int* esrc = ei;
  const int* edst = ei + NE;

  hipMemsetAsync(cnt, 0, (size_t)NN * 4, stream);
  hipMemsetAsync(cursor, 0, (size_t)NN * 4, stream);
  count_k<<<NE / 256, 256, 0, stream>>>(edst, cnt);
  dinv_k<<<(NN + 255) / 256, 256, 0, stream>>>(cnt, dinv);
  scan1<<<98, 1024, 0, stream>>>(cnt, rowstart, blocksum);
  scan2<<<1, 1, 0, stream>>>(blocksum, 98);
  scan3<<<98, 1024, 0, stream>>>(rowstart, blocksum);
  fill_k<<<NE / 256, 256, 0, stream>>>(esrc, edst, rowstart, cursor, csr);

  // feature branch: h = relu(gcn(x,Wg1,bg1)); h2 = gcn(h,Wg2,bg2)
  gemm_k<128, 0, 128, 32, 0, true, false, true><<<NN / 32, 256, 0, stream>>>(x, nullptr, Wg1, nullptr, dinv, Tb);
  agg_k<128, 1><<<NN / 16, 256, 0, stream>>>((const uint4*)Tb, rowstart, cnt, csr, dinv, bg1, H);
  gemm_k<128, 0, 128, 32, 0, true, false, true><<<NN / 32, 256, 0, stream>>>(H, nullptr, Wg2, nullptr, dinv, Tb);
  agg_k<128, 0><<<NN / 16, 256, 0, stream>>>((const uint4*)Tb, rowstart, cnt, csr, dinv, bg2, H);

  // label branch: 10 layers, relu except last
  const float* xl = y;
  for (int j = 0; j < 10; ++j) {
    gemm_k<64, 0, 64, 64, 0, true, false, true><<<(NN + 63) / 64, 256, 0, stream>>>(
        xl, nullptr, Wl + (size_t)j * 64 * 64, nullptr, dinv, Ub);
    float* nxt = (j & 1) ? XL1 : XL0;
    if (j < 9)
      agg_k<64, 1><<<NN / 32, 256, 0, stream>>>((const uint4*)Ub, rowstart, cnt, csr, dinv, bl + (size_t)j * 64, nxt);
    else
      agg_k<64, 0><<<NN / 32, 256, 0, stream>>>((const uint4*)Ub, rowstart, cnt, csr, dinv, bl + (size_t)j * 64, nxt);
    xl = nxt;
  }

  // fused head: sigmoid([h2 | xl] @ Wf + bf), xl ended in XL1 (j=9 odd)
  gemm_k<128, 64, 64, 64, 2, false, true, false><<<(NN + 63) / 64, 256, 0, stream>>>(H, xl, Wf, bf, nullptr, out);
}